// Round 16
// baseline (781.789 us; speedup 1.0000x reference)
//
#include <hip/hip_runtime.h>

#define NN 50000
#define NE 800000
#define NG 128
#define HD 128
#define NL 4
#define BN_EPS 1e-5f
#define REP 32
#define WP 136
#define NB 392
#define EPB 4096

typedef __attribute__((ext_vector_type(8))) short bf16x8;
typedef __attribute__((ext_vector_type(4))) float f32x4;

__device__ __forceinline__ unsigned short f2bf(float f) {
    unsigned u = __float_as_uint(f);
    u += 0x7FFFu + ((u >> 16) & 1u);  // RNE
    return (unsigned short)(u >> 16);
}
__device__ __forceinline__ float bfval(unsigned short h) { return __uint_as_float((unsigned)h << 16); }
__device__ __forceinline__ float bflo(unsigned u) { return __uint_as_float(u << 16); }
__device__ __forceinline__ float bfhi(unsigned u) { return __uint_as_float(u & 0xFFFF0000u); }

__device__ __forceinline__ void split2(float a, float b, unsigned& hi, unsigned& lo) {
    unsigned ua = __float_as_uint(a), ub = __float_as_uint(b);
    hi = (ua >> 16) | (ub & 0xFFFF0000u);
    float ra = a - __uint_as_float(ua & 0xFFFF0000u);
    float rb = b - __uint_as_float(ub & 0xFFFF0000u);
    lo = (unsigned)f2bf(ra) | ((unsigned)f2bf(rb) << 16);
}
__device__ __forceinline__ unsigned pack2(float a, float b) {
    return (unsigned)f2bf(a) | ((unsigned)f2bf(b) << 16);
}

__device__ __forceinline__ void bn_pre(const float* SQbase,
                                       const float* gam, const float* bet,
                                       float inv_cnt, int t, float* scs, float* shs) {
    if (gam == nullptr) { scs[t] = 1.f; shs[t] = 0.f; return; }
    float s = 0.f, q = 0.f;
#pragma unroll
    for (int r = 0; r < REP; r++) {
        s += SQbase[r * 256 + t];
        q += SQbase[r * 256 + 128 + t];
    }
    float m = s * inv_cnt;
    float var = fmaxf(fmaf(q, inv_cnt, -m * m), 0.f);
    float inv = rsqrtf(var + BN_EPS);
    float sc = gam[t] * inv;
    scs[t] = sc;
    shs[t] = fmaf(-m, sc, bet[t]);
}

// ---------------- fused setup: embed (3125) | cvtw (640) | hist (3125) ----------------
__global__ __launch_bounds__(256) void setup_kernel(const int* __restrict__ ids,
                                                    const float* __restrict__ emb,
                                                    unsigned short* __restrict__ Yb,
                                                    const float* __restrict__ iw1,
                                                    const float* __restrict__ iw2,
                                                    const float* __restrict__ mw1,
                                                    const float* __restrict__ mw2,
                                                    unsigned short* __restrict__ Wh,
                                                    unsigned short* __restrict__ Wl,
                                                    const int* __restrict__ dst,
                                                    int* __restrict__ deg) {
    int b = blockIdx.x, t = threadIdx.x;
    if (b < 3125) {
        int i = b * 256 + t;
        if (i < NN * 16) {
            int node = i >> 4, g = i & 15;
            int id = ids[node];
            const float* p = emb + (size_t)id * HD + 8 * g;
            float4 a = *(const float4*)p;
            float4 bb = *(const float4*)(p + 4);
            uint4 o;
            o.x = pack2(a.x, a.y); o.y = pack2(a.z, a.w);
            o.z = pack2(bb.x, bb.y); o.w = pack2(bb.z, bb.w);
            *(uint4*)(Yb + (size_t)node * HD + 8 * g) = o;
        }
    } else if (b < 3765) {
        int i = (b - 3125) * 256 + t;
        if (i < 163840) {
            int seg = i >> 14, loc = i & 16383;
            float v;
            if (seg == 0)      v = iw1[loc];
            else if (seg == 1) v = iw2[loc];
            else if (seg < 6)  v = mw1[(seg - 2) * 16384 + loc];
            else               v = mw2[(seg - 6) * 16384 + loc];
            int k = loc >> 7, n = loc & 127;
            unsigned short h = f2bf(v);
            float r = v - bfval(h);
            Wh[seg * 16384 + n * 128 + k] = h;
            Wl[seg * 16384 + n * 128 + k] = f2bf(r);
        }
    } else {
        int e = (b - 3765) * 256 + t;
        if (e < NE) atomicAdd(&deg[dst[e]], 1);
    }
}

// ---------------- ybn ----------------
__global__ __launch_bounds__(256) void ybn_kernel(const float* __restrict__ X,
                                                  const float* __restrict__ SQin,
                                                  const float* __restrict__ gam,
                                                  const float* __restrict__ bet,
                                                  unsigned short* __restrict__ Yb) {
    __shared__ float scs[HD], shs[HD];
    int t = threadIdx.x;
    if (t < HD) bn_pre(SQin, gam, bet, 1.f / NN, t, scs, shs);
    __syncthreads();
    int row = blockIdx.x * 16 + (t >> 4);
    int c8 = (t & 15) * 8;
    if (row < NN) {
        const float* p = X + (size_t)row * HD + c8;
        float4 v0 = *(const float4*)p;
        float4 v1 = *(const float4*)(p + 4);
        float4 s0 = *(const float4*)&scs[c8], s1 = *(const float4*)&scs[c8 + 4];
        float4 h0 = *(const float4*)&shs[c8], h1 = *(const float4*)&shs[c8 + 4];
        float f0 = fmaxf(fmaf(v0.x, s0.x, h0.x), 0.f), f1 = fmaxf(fmaf(v0.y, s0.y, h0.y), 0.f);
        float f2 = fmaxf(fmaf(v0.z, s0.z, h0.z), 0.f), f3 = fmaxf(fmaf(v0.w, s0.w, h0.w), 0.f);
        float f4 = fmaxf(fmaf(v1.x, s1.x, h1.x), 0.f), f5 = fmaxf(fmaf(v1.y, s1.y, h1.y), 0.f);
        float f6 = fmaxf(fmaf(v1.z, s1.z, h1.z), 0.f), f7 = fmaxf(fmaf(v1.w, s1.w, h1.w), 0.f);
        uint4 o;
        o.x = pack2(f0, f1); o.y = pack2(f2, f3);
        o.z = pack2(f4, f5); o.w = pack2(f6, f7);
        *(uint4*)(Yb + (size_t)row * HD + c8) = o;
    }
}

// ---------------- CSR scans ----------------
__global__ __launch_bounds__(1024) void scan1_kernel(const int* __restrict__ deg,
                                                     int* __restrict__ rowptr,
                                                     int* __restrict__ blockSum) {
    __shared__ int s[1024];
    int b = blockIdx.x, t = threadIdx.x;
    int i = b * 1024 + t;
    int v = (i < NN) ? deg[i] : 0;
    s[t] = v;
    __syncthreads();
    for (int off = 1; off < 1024; off <<= 1) {
        int u = (t >= off) ? s[t - off] : 0;
        __syncthreads();
        s[t] += u;
        __syncthreads();
    }
    if (i < NN) rowptr[i] = s[t] - v;
    if (t == 1023) blockSum[b] = s[1023];
}

__global__ __launch_bounds__(64) void scan2_kernel(const int* __restrict__ blockSum,
                                                   int* __restrict__ blockOff,
                                                   int* __restrict__ rowptr, int nblocks) {
    int t = threadIdx.x;
    int orig = (t < nblocks) ? blockSum[t] : 0;
    int v = orig;
    for (int off = 1; off < 64; off <<= 1) {
        int u = __shfl_up(v, off, 64);
        if (t >= off) v += u;
    }
    if (t < nblocks) blockOff[t] = v - orig;
    if (t == nblocks - 1) rowptr[NN] = v;
}

__global__ __launch_bounds__(1024) void scan3_kernel(int* __restrict__ rowptr,
                                                     int* __restrict__ cursor,
                                                     const int* __restrict__ blockOff,
                                                     int* __restrict__ bucketCursor) {
    int b = blockIdx.x, t = threadIdx.x;
    int i = b * 1024 + t;
    if (i < NN) {
        int r = rowptr[i] + blockOff[b];
        rowptr[i] = r;
        cursor[i] = r;
        if ((i & 127) == 0) bucketCursor[i >> 7] = r;
    }
}

// ---------------- bin ----------------
__global__ __launch_bounds__(256) void bin_kernel(const int* __restrict__ src,
                                                  const int* __restrict__ dst,
                                                  const int* __restrict__ attr,
                                                  int* __restrict__ bucketCursor,
                                                  uint2* __restrict__ ebuf) {
    __shared__ int cnt[512];
    __shared__ int sc[512], sc2[512];
    __shared__ int base[512];
    __shared__ int garr[NB];
    __shared__ int wof[NB];
    __shared__ uint2 stage[EPB];
    int t = threadIdx.x;
    int e0 = blockIdx.x * EPB;
    for (int i = t; i < 512; i += 256) cnt[i] = 0;
    __syncthreads();
    int myb[16]; unsigned myv[16]; int myd[16];
#pragma unroll
    for (int j = 0; j < 16; j++) {
        int e = e0 + t + j * 256;
        if (e < NE) {
            int d = dst[e];
            myd[j] = d;
            myv[j] = (unsigned)src[e] | ((unsigned)attr[e] << 16);
            myb[j] = d >> 7;
            atomicAdd(&cnt[myb[j]], 1);
        } else myb[j] = -1;
    }
    __syncthreads();
    for (int k = t; k < 512; k += 256) sc[k] = cnt[k];
    __syncthreads();
    int* sp = sc; int* dp = sc2;
    for (int off = 1; off < 512; off <<= 1) {
        for (int k = t; k < 512; k += 256) dp[k] = sp[k] + (k >= off ? sp[k - off] : 0);
        __syncthreads();
        int* tmp = sp; sp = dp; dp = tmp;
    }
    for (int k = t; k < 512; k += 256) base[k] = sp[k] - cnt[k];
    int total = sp[511];
    __syncthreads();
    for (int b = t; b < NB; b += 256) {
        wof[b] = 0;
        if (cnt[b] > 0) garr[b] = atomicAdd(&bucketCursor[b], cnt[b]);
    }
    __syncthreads();
#pragma unroll
    for (int j = 0; j < 16; j++) {
        if (myb[j] >= 0) {
            int slot = base[myb[j]] + atomicAdd(&wof[myb[j]], 1);
            stage[slot] = make_uint2(myv[j], (unsigned)myd[j]);
        }
    }
    __syncthreads();
    for (int i = t; i < total; i += 256) {
        uint2 u = stage[i];
        int b = (int)(u.y >> 7);
        ebuf[garr[b] + (i - base[b])] = u;
    }
}

// ---------------- place ----------------
__global__ __launch_bounds__(256) void place_kernel(const uint2* __restrict__ ebuf,
                                                    const int* __restrict__ rowptr,
                                                    int* __restrict__ cursor,
                                                    unsigned* __restrict__ csr) {
    int b = blockIdx.x;
    int n0 = b * 128;
    int n1 = n0 + 128; if (n1 > NN) n1 = NN;
    int es = rowptr[n0], ee = rowptr[n1];
    for (int i = es + threadIdx.x; i < ee; i += 256) {
        uint2 u = ebuf[i];
        int pos = atomicAdd(&cursor[u.y], 1);
        csr[pos] = u.x;
    }
}

// ---------------- GINE conv ----------------
__device__ __forceinline__ void gine_acc(const unsigned short* __restrict__ Yb,
                                         const float* __restrict__ elds,
                                         unsigned p, int cq, float mask, float* a) {
    uint4 q = *(const uint4*)(Yb + (size_t)(p & 0xFFFFu) * HD + 8 * cq);
    const float* ep = elds + (p >> 16) * HD + 8 * cq;
    float4 e0 = *(const float4*)ep;
    float4 e1 = *(const float4*)(ep + 4);
    a[0] += mask * fmaxf(bflo(q.x) + e0.x, 0.f);
    a[1] += mask * fmaxf(bfhi(q.x) + e0.y, 0.f);
    a[2] += mask * fmaxf(bflo(q.y) + e0.z, 0.f);
    a[3] += mask * fmaxf(bfhi(q.y) + e0.w, 0.f);
    a[4] += mask * fmaxf(bflo(q.z) + e1.x, 0.f);
    a[5] += mask * fmaxf(bfhi(q.z) + e1.y, 0.f);
    a[6] += mask * fmaxf(bflo(q.w) + e1.z, 0.f);
    a[7] += mask * fmaxf(bfhi(q.w) + e1.w, 0.f);
}

__global__ __launch_bounds__(256) void conv_kernel(const unsigned short* __restrict__ Yb,
                                                   const int* __restrict__ rowptr,
                                                   const unsigned* __restrict__ csr,
                                                   const float* __restrict__ edge_emb,
                                                   const float* __restrict__ eps, int layer,
                                                   unsigned short* __restrict__ Ah,
                                                   unsigned short* __restrict__ Al) {
    __shared__ float elds[8 * HD];
    int t = threadIdx.x;
    ((float4*)elds)[t] = ((const float4*)edge_emb)[t];
    __syncthreads();
    int wave = t >> 6, lane = t & 63;
    int node = blockIdx.x * 4 + wave;
    if (node >= NN) return;
    int sub = lane >> 4, cq = lane & 15;
    int lo = rowptr[node], hi = rowptr[node + 1];
    float a[8];
#pragma unroll
    for (int i = 0; i < 8; i++) a[i] = 0.f;
    for (int base = lo; base < hi; base += 64) {
        unsigned pl = 0;
        int cnt = hi - base; if (cnt > 64) cnt = 64;
        if (base + lane < hi) pl = csr[base + lane];
        int j = 0;
        for (; j + 16 <= cnt; j += 16) {
            unsigned pa = __shfl(pl, j + sub, 64);
            unsigned pb = __shfl(pl, j + 4 + sub, 64);
            unsigned pc = __shfl(pl, j + 8 + sub, 64);
            unsigned pd = __shfl(pl, j + 12 + sub, 64);
            gine_acc(Yb, elds, pa, cq, 1.f, a);
            gine_acc(Yb, elds, pb, cq, 1.f, a);
            gine_acc(Yb, elds, pc, cq, 1.f, a);
            gine_acc(Yb, elds, pd, cq, 1.f, a);
        }
        for (; j + 8 <= cnt; j += 8) {
            unsigned pa = __shfl(pl, j + sub, 64);
            unsigned pb = __shfl(pl, j + 4 + sub, 64);
            gine_acc(Yb, elds, pa, cq, 1.f, a);
            gine_acc(Yb, elds, pb, cq, 1.f, a);
        }
        for (; j < cnt; j += 4) {
            int je = j + sub;
            bool val = (je < cnt);
            unsigned p = __shfl(pl, val ? je : j, 64);
            gine_acc(Yb, elds, p, cq, val ? 1.f : 0.f, a);
        }
    }
#pragma unroll
    for (int i = 0; i < 8; i++) {
        a[i] += __shfl_xor(a[i], 16, 64);
        a[i] += __shfl_xor(a[i], 32, 64);
    }
    if (sub == 0) {
        float g = 1.f + eps[layer];
        uint4 q = *(const uint4*)(Yb + (size_t)node * HD + 8 * cq);
        float o0 = fmaf(g, bflo(q.x), a[0]), o1 = fmaf(g, bfhi(q.x), a[1]);
        float o2 = fmaf(g, bflo(q.y), a[2]), o3 = fmaf(g, bfhi(q.y), a[3]);
        float o4 = fmaf(g, bflo(q.z), a[4]), o5 = fmaf(g, bfhi(q.z), a[5]);
        float o6 = fmaf(g, bflo(q.w), a[6]), o7 = fmaf(g, bfhi(q.w), a[7]);
        uint4 H, L;
        split2(o0, o1, H.x, L.x);
        split2(o2, o3, H.y, L.y);
        split2(o4, o5, H.z, L.z);
        split2(o6, o7, H.w, L.w);
        *(uint4*)(Ah + (size_t)node * HD + 8 * cq) = H;
        *(uint4*)(Al + (size_t)node * HD + 8 * cq) = L;
    }
}

// ---------------- MFMA matmul, pre-split A, W in LDS; 2 row-tiles/wave ----------------
__global__ __launch_bounds__(256) void mm_mfma_pre(const unsigned short* __restrict__ Ah,
                                                   const unsigned short* __restrict__ Al,
                                                   const unsigned short* __restrict__ Wh,
                                                   const unsigned short* __restrict__ Wl,
                                                   const float* __restrict__ bias,
                                                   float* __restrict__ out,
                                                   float* __restrict__ SQout) {
    __shared__ unsigned short WhS[64 * WP];
    __shared__ unsigned short WlS[64 * WP];
    int t = threadIdx.x;
    int rowblk = blockIdx.x >> 1;
    int colbase = (blockIdx.x & 1) * 64;
    const unsigned short* sh = Wh + (size_t)colbase * HD;
    const unsigned short* sl = Wl + (size_t)colbase * HD;
#pragma unroll
    for (int i = 0; i < 4; i++) {
        int idx = t + i * 256;
        int col = idx >> 4, kk = (idx & 15) * 8;
        *(uint4*)(WhS + col * WP + kk) = *(const uint4*)(sh + (size_t)col * HD + kk);
        *(uint4*)(WlS + col * WP + kk) = *(const uint4*)(sl + (size_t)col * HD + kk);
    }
    __syncthreads();
    int w = t >> 6, lane = t & 63;
    int quad = lane >> 4, nl = lane & 15;
    int row0 = rowblk * 128 + w * 32;
    int rA0 = row0 + nl, rA1 = row0 + 16 + nl;
    bool ok0 = rA0 < NN, ok1 = rA1 < NN;
    f32x4 acc[8];
#pragma unroll
    for (int i = 0; i < 8; i++) acc[i] = (f32x4){0.f, 0.f, 0.f, 0.f};
#pragma unroll
    for (int kc = 0; kc < 4; kc++) {
        int k0 = kc * 32 + quad * 8;
        bf16x8 a0h = ok0 ? *(const bf16x8*)(Ah + (size_t)rA0 * HD + k0) : (bf16x8)0;
        bf16x8 a0l = ok0 ? *(const bf16x8*)(Al + (size_t)rA0 * HD + k0) : (bf16x8)0;
        bf16x8 a1h = ok1 ? *(const bf16x8*)(Ah + (size_t)rA1 * HD + k0) : (bf16x8)0;
        bf16x8 a1l = ok1 ? *(const bf16x8*)(Al + (size_t)rA1 * HD + k0) : (bf16x8)0;
#pragma unroll
        for (int c = 0; c < 4; c++) {
            int wof = (c * 16 + nl) * WP + k0;
            bf16x8 bh = *(const bf16x8*)(WhS + wof);
            bf16x8 bl = *(const bf16x8*)(WlS + wof);
            acc[c] = __builtin_amdgcn_mfma_f32_16x16x32_bf16(a0h, bh, acc[c], 0, 0, 0);
            acc[c] = __builtin_amdgcn_mfma_f32_16x16x32_bf16(a0l, bh, acc[c], 0, 0, 0);
            acc[c] = __builtin_amdgcn_mfma_f32_16x16x32_bf16(a0h, bl, acc[c], 0, 0, 0);
            acc[4 + c] = __builtin_amdgcn_mfma_f32_16x16x32_bf16(a1h, bh, acc[4 + c], 0, 0, 0);
            acc[4 + c] = __builtin_amdgcn_mfma_f32_16x16x32_bf16(a1l, bh, acc[4 + c], 0, 0, 0);
            acc[4 + c] = __builtin_amdgcn_mfma_f32_16x16x32_bf16(a1h, bl, acc[4 + c], 0, 0, 0);
        }
    }
    int rep = (blockIdx.x & (REP - 1)) * 256;
#pragma unroll
    for (int h = 0; h < 2; h++) {
        int baserow = row0 + h * 16 + quad * 4;
#pragma unroll
        for (int c = 0; c < 4; c++) {
            int col = colbase + c * 16 + nl;
            float bv = bias ? bias[col] : 0.f;
            f32x4 v = acc[h * 4 + c];
            float s = 0.f, qq = 0.f;
#pragma unroll
            for (int r = 0; r < 4; r++) {
                int grow = baserow + r;
                float val = v[r] + bv;
                if (grow < NN) {
                    out[(size_t)grow * HD + col] = val;
                    s += val;
                    qq += val * val;
                }
            }
            s += __shfl_xor(s, 16, 64);  s += __shfl_xor(s, 32, 64);
            qq += __shfl_xor(qq, 16, 64); qq += __shfl_xor(qq, 32, 64);
            if (quad == 0) {
                atomicAdd(&SQout[rep + col], s);
                atomicAdd(&SQout[rep + 128 + col], qq);
            }
        }
    }
}

// ---------------- MFMA matmul, fp32 A + fused BN-act + split, W in LDS; 2 row-tiles ----------
__global__ __launch_bounds__(256) void mm_mfma_act(const float* __restrict__ A,
                                                   const unsigned short* __restrict__ Wh,
                                                   const unsigned short* __restrict__ Wl,
                                                   const float* __restrict__ bias,
                                                   const float* __restrict__ SQin,
                                                   const float* __restrict__ gam,
                                                   const float* __restrict__ bet,
                                                   float* __restrict__ out,
                                                   float* __restrict__ SQout) {
    __shared__ unsigned short WhS[64 * WP];
    __shared__ unsigned short WlS[64 * WP];
    __shared__ float scs[HD], shs[HD];
    int t = threadIdx.x;
    int rowblk = blockIdx.x >> 1;
    int colbase = (blockIdx.x & 1) * 64;
    if (t < HD) bn_pre(SQin, gam, bet, 1.f / NN, t, scs, shs);
    const unsigned short* sh = Wh + (size_t)colbase * HD;
    const unsigned short* sl = Wl + (size_t)colbase * HD;
#pragma unroll
    for (int i = 0; i < 4; i++) {
        int idx = t + i * 256;
        int col = idx >> 4, kk = (idx & 15) * 8;
        *(uint4*)(WhS + col * WP + kk) = *(const uint4*)(sh + (size_t)col * HD + kk);
        *(uint4*)(WlS + col * WP + kk) = *(const uint4*)(sl + (size_t)col * HD + kk);
    }
    __syncthreads();
    int w = t >> 6, lane = t & 63;
    int quad = lane >> 4, nl = lane & 15;
    int row0 = rowblk * 128 + w * 32;
    int rA0 = row0 + nl, rA1 = row0 + 16 + nl;
    bool ok0 = rA0 < NN, ok1 = rA1 < NN;
    f32x4 acc[8];
#pragma unroll
    for (int i = 0; i < 8; i++) acc[i] = (f32x4){0.f, 0.f, 0.f, 0.f};
#pragma unroll
    for (int kc = 0; kc < 4; kc++) {
        int k0 = kc * 32 + quad * 8;
        float4 s0 = *(const float4*)&scs[k0], s1 = *(const float4*)&scs[k0 + 4];
        float4 t0 = *(const float4*)&shs[k0], t1 = *(const float4*)&shs[k0 + 4];
        bf16x8 a0h, a0l, a1h, a1l;
        {
            float4 v0 = ok0 ? *(const float4*)(A + (size_t)rA0 * HD + k0) : make_float4(0, 0, 0, 0);
            float4 v1 = ok0 ? *(const float4*)(A + (size_t)rA0 * HD + k0 + 4) : make_float4(0, 0, 0, 0);
            float f0 = fmaxf(fmaf(v0.x, s0.x, t0.x), 0.f), f1 = fmaxf(fmaf(v0.y, s0.y, t0.y), 0.f);
            float f2 = fmaxf(fmaf(v0.z, s0.z, t0.z), 0.f), f3 = fmaxf(fmaf(v0.w, s0.w, t0.w), 0.f);
            float f4 = fmaxf(fmaf(v1.x, s1.x, t1.x), 0.f), f5 = fmaxf(fmaf(v1.y, s1.y, t1.y), 0.f);
            float f6 = fmaxf(fmaf(v1.z, s1.z, t1.z), 0.f), f7 = fmaxf(fmaf(v1.w, s1.w, t1.w), 0.f);
            if (!ok0) { f0 = f1 = f2 = f3 = f4 = f5 = f6 = f7 = 0.f; }
            unsigned h0, h1, h2, h3, l0, l1, l2, l3;
            split2(f0, f1, h0, l0); split2(f2, f3, h1, l1);
            split2(f4, f5, h2, l2); split2(f6, f7, h3, l3);
            a0h = __builtin_bit_cast(bf16x8, make_uint4(h0, h1, h2, h3));
            a0l = __builtin_bit_cast(bf16x8, make_uint4(l0, l1, l2, l3));
        }
        {
            float4 v0 = ok1 ? *(const float4*)(A + (size_t)rA1 * HD + k0) : make_float4(0, 0, 0, 0);
            float4 v1 = ok1 ? *(const float4*)(A + (size_t)rA1 * HD + k0 + 4) : make_float4(0, 0, 0, 0);
            float f0 = fmaxf(fmaf(v0.x, s0.x, t0.x), 0.f), f1 = fmaxf(fmaf(v0.y, s0.y, t0.y), 0.f);
            float f2 = fmaxf(fmaf(v0.z, s0.z, t0.z), 0.f), f3 = fmaxf(fmaf(v0.w, s0.w, t0.w), 0.f);
            float f4 = fmaxf(fmaf(v1.x, s1.x, t1.x), 0.f), f5 = fmaxf(fmaf(v1.y, s1.y, t1.y), 0.f);
            float f6 = fmaxf(fmaf(v1.z, s1.z, t1.z), 0.f), f7 = fmaxf(fmaf(v1.w, s1.w, t1.w), 0.f);
            if (!ok1) { f0 = f1 = f2 = f3 = f4 = f5 = f6 = f7 = 0.f; }
            unsigned h0, h1, h2, h3, l0, l1, l2, l3;
            split2(f0, f1, h0, l0); split2(f2, f3, h1, l1);
            split2(f4, f5, h2, l2); split2(f6, f7, h3, l3);
            a1h = __builtin_bit_cast(bf16x8, make_uint4(h0, h1, h2, h3));
            a1l = __builtin_bit_cast(bf16x8, make_uint4(l0, l1, l2, l3));
        }
#pragma unroll
        for (int c = 0; c < 4; c++) {
            int wof = (c * 16 + nl) * WP + k0;
            bf16x8 bh = *(const bf16x8*)(WhS + wof);
            bf16x8 bl = *(const bf16x8*)(WlS + wof);
            acc[c] = __builtin_amdgcn_mfma_f32_16x16x32_bf16(a0h, bh, acc[c], 0, 0, 0);
            acc[c] = __builtin_amdgcn_mfma_f32_16x16x32_bf16(a0l, bh, acc[c], 0, 0, 0);
            acc[c] = __builtin_amdgcn_mfma_f32_16x16x32_bf16(a0h, bl, acc[c], 0, 0, 0);
            acc[4 + c] = __builtin_amdgcn_mfma_f32_16x16x32_bf16(a1h, bh, acc[4 + c], 0, 0, 0);
            acc[4 + c] = __builtin_amdgcn_mfma_f32_16x16x32_bf16(a1l, bh, acc[4 + c], 0, 0, 0);
            acc[4 + c] = __builtin_amdgcn_mfma_f32_16x16x32_bf16(a1h, bl, acc[4 + c], 0, 0, 0);
        }
    }
    int rep = (blockIdx.x & (REP - 1)) * 256;
#pragma unroll
    for (int h = 0; h < 2; h++) {
        int baserow = row0 + h * 16 + quad * 4;
#pragma unroll
        for (int c = 0; c < 4; c++) {
            int col = colbase + c * 16 + nl;
            float bv = bias ? bias[col] : 0.f;
            f32x4 v = acc[h * 4 + c];
            float s = 0.f, qq = 0.f;
#pragma unroll
            for (int r = 0; r < 4; r++) {
                int grow = baserow + r;
                float val = v[r] + bv;
                if (grow < NN) {
                    out[(size_t)grow * HD + col] = val;
                    s += val;
                    qq += val * val;
                }
            }
            s += __shfl_xor(s, 16, 64);  s += __shfl_xor(s, 32, 64);
            qq += __shfl_xor(qq, 16, 64); qq += __shfl_xor(qq, 32, 64);
            if (quad == 0) {
                atomicAdd(&SQout[rep + col], s);
                atomicAdd(&SQout[rep + 128 + col], qq);
            }
        }
    }
}

// ---------------- readout ----------------
__global__ __launch_bounds__(256) void readout_kernel(const float* __restrict__ x,
                                                      const int* __restrict__ batch,
                                                      const float* __restrict__ SQin,
                                                      const float* __restrict__ gam,
                                                      const float* __restrict__ bet,
                                                      float* __restrict__ gout) {
    __shared__ int bat[256];
    __shared__ float scs[HD], shs[HD];
    int t = threadIdx.x;
    int rq = t >> 5, cq = t & 31;
    int r0 = blockIdx.x * 256;
    int i = r0 + t;
    bat[t] = (i < NN) ? batch[i] : -1;
    if (t < HD) bn_pre(SQin, gam, bet, 1.f / NN, t, scs, shs);
    __syncthreads();
    float4 s4 = *(const float4*)&scs[4 * cq];
    float4 h4 = *(const float4*)&shs[4 * cq];
    float4 acc = make_float4(0.f, 0.f, 0.f, 0.f);
    int gcur = -1;
    for (int j = rq; j < 256; j += 8) {
        int r = r0 + j;
        if (r >= NN) break;
        int g = bat[j];
        if (g != gcur) {
            if (gcur >= 0) {
                atomicAdd(&gout[(size_t)gcur * HD + 4 * cq + 0], acc.x);
                atomicAdd(&gout[(size_t)gcur * HD + 4 * cq + 1], acc.y);
                atomicAdd(&gout[(size_t)gcur * HD + 4 * cq + 2], acc.z);
                atomicAdd(&gout[(size_t)gcur * HD + 4 * cq + 3], acc.w);
            }
            acc = make_float4(0.f, 0.f, 0.f, 0.f);
            gcur = g;
        }
        float4 v = *(const float4*)(x + (size_t)r * HD + 4 * cq);
        acc.x += fmaxf(fmaf(v.x, s4.x, h4.x), 0.f);
        acc.y += fmaxf(fmaf(v.y, s4.y, h4.y), 0.f);
        acc.z += fmaxf(fmaf(v.z, s4.z, h4.z), 0.f);
        acc.w += fmaxf(fmaf(v.w, s4.w, h4.w), 0.f);
    }
    if (gcur >= 0) {
        atomicAdd(&gout[(size_t)gcur * HD + 4 * cq + 0], acc.x);
        atomicAdd(&gout[(size_t)gcur * HD + 4 * cq + 1], acc.y);
        atomicAdd(&gout[(size_t)gcur * HD + 4 * cq + 2], acc.z);
        atomicAdd(&gout[(size_t)gcur * HD + 4 * cq + 3], acc.w);
    }
}

// ---------------- fused head: 4 matmuls + BNs + final dot; 2 blocks + spin barrier ----------
__device__ __forceinline__ void head_phase(const float* __restrict__ A,
                                           const float* __restrict__ W,
                                           const float* __restrict__ SQin,
                                           const float* __restrict__ gam,
                                           const float* __restrict__ bet,
                                           float* __restrict__ out,
                                           float* __restrict__ SQout,
                                           int bid, int t,
                                           float* As, float* colS, float* colQ,
                                           float* scs, float* shs) {
    const int PADK = 132;
    if (t < HD) {
        colS[t] = 0.f; colQ[t] = 0.f;
        bn_pre(SQin, gam, bet, 1.f / NG, t, scs, shs);
    }
    __syncthreads();
    int row0 = bid * 64;
#pragma unroll
    for (int i = 0; i < 8; i++) {
        int idx = t + i * 256;
        int r = idx >> 5, kq = idx & 31;
        float4 v = *(const float4*)(A + (size_t)(row0 + r) * HD + 4 * kq);
        float4 s4 = *(const float4*)&scs[4 * kq];
        float4 h4 = *(const float4*)&shs[4 * kq];
        v.x = fmaxf(fmaf(v.x, s4.x, h4.x), 0.f);
        v.y = fmaxf(fmaf(v.y, s4.y, h4.y), 0.f);
        v.z = fmaxf(fmaf(v.z, s4.z, h4.z), 0.f);
        v.w = fmaxf(fmaf(v.w, s4.w, h4.w), 0.f);
        *(float4*)&As[r * PADK + 4 * kq] = v;
    }
    __syncthreads();
    int jq = t & 31, rb = t >> 5;
    float acc[8][4];
#pragma unroll
    for (int i = 0; i < 8; i++)
#pragma unroll
        for (int j = 0; j < 4; j++) acc[i][j] = 0.f;
    const float* Wp = W + 4 * jq;
    const float* Ap = &As[rb * 8 * PADK];
    for (int k = 0; k < HD; k += 4) {
        float4 w0 = *(const float4*)(Wp + (size_t)(k + 0) * HD);
        float4 w1 = *(const float4*)(Wp + (size_t)(k + 1) * HD);
        float4 w2 = *(const float4*)(Wp + (size_t)(k + 2) * HD);
        float4 w3 = *(const float4*)(Wp + (size_t)(k + 3) * HD);
#pragma unroll
        for (int i = 0; i < 8; i++) {
            float4 a4 = *(const float4*)&Ap[i * PADK + k];
            acc[i][0] = fmaf(a4.x, w0.x, acc[i][0]);
            acc[i][1] = fmaf(a4.x, w0.y, acc[i][1]);
            acc[i][2] = fmaf(a4.x, w0.z, acc[i][2]);
            acc[i][3] = fmaf(a4.x, w0.w, acc[i][3]);
            acc[i][0] = fmaf(a4.y, w1.x, acc[i][0]);
            acc[i][1] = fmaf(a4.y, w1.y, acc[i][1]);
            acc[i][2] = fmaf(a4.y, w1.z, acc[i][2]);
            acc[i][3] = fmaf(a4.y, w1.w, acc[i][3]);
            acc[i][0] = fmaf(a4.z, w2.x, acc[i][0]);
            acc[i][1] = fmaf(a4.z, w2.y, acc[i][1]);
            acc[i][2] = fmaf(a4.z, w2.z, acc[i][2]);
            acc[i][3] = fmaf(a4.z, w2.w, acc[i][3]);
            acc[i][0] = fmaf(a4.w, w3.x, acc[i][0]);
            acc[i][1] = fmaf(a4.w, w3.y, acc[i][1]);
            acc[i][2] = fmaf(a4.w, w3.z, acc[i][2]);
            acc[i][3] = fmaf(a4.w, w3.w, acc[i][3]);
        }
    }
    float s0 = 0, s1 = 0, s2 = 0, s3 = 0, q0 = 0, q1 = 0, q2 = 0, q3 = 0;
#pragma unroll
    for (int i = 0; i < 8; i++) {
        int gr = row0 + rb * 8 + i;
        float4 v = make_float4(acc[i][0], acc[i][1], acc[i][2], acc[i][3]);
        *(float4*)(out + (size_t)gr * HD + 4 * jq) = v;
        s0 += v.x; q0 += v.x * v.x;
        s1 += v.y; q1 += v.y * v.y;
        s2 += v.z; q2 += v.z * v.z;
        s3 += v.w; q3 += v.w * v.w;
    }
    atomicAdd(&colS[4 * jq + 0], s0); atomicAdd(&colQ[4 * jq + 0], q0);
    atomicAdd(&colS[4 * jq + 1], s1); atomicAdd(&colQ[4 * jq + 1], q1);
    atomicAdd(&colS[4 * jq + 2], s2); atomicAdd(&colQ[4 * jq + 2], q2);
    atomicAdd(&colS[4 * jq + 3], s3); atomicAdd(&colQ[4 * jq + 3], q3);
    __syncthreads();
    int rep = bid * 256;
    if (t < HD) {
        atomicAdd(&SQout[rep + t], colS[t]);
        atomicAdd(&SQout[rep + 128 + t], colQ[t]);
    }
}

__device__ __forceinline__ void grid_bar2(volatile int* hb, int i, int t) {
    __syncthreads();
    __threadfence();
    if (t == 0) {
        atomicAdd((int*)&hb[i], 1);
        while (atomicAdd((int*)&hb[i], 0) < 2) { }
    }
    __syncthreads();
}

__global__ __launch_bounds__(256) void head_all(const float* __restrict__ Gp,
                                                const float* __restrict__ l1W1,
                                                const float* __restrict__ l1g1, const float* __restrict__ l1b1,
                                                const float* __restrict__ l1W2,
                                                const float* __restrict__ l1g2, const float* __restrict__ l1b2,
                                                const float* __restrict__ l2W1,
                                                const float* __restrict__ l2g1, const float* __restrict__ l2b1,
                                                const float* __restrict__ l2W2,
                                                const float* __restrict__ l2g2, const float* __restrict__ l2b2,
                                                const float* __restrict__ finW,
                                                float* __restrict__ Hp, float* __restrict__ Hp2,
                                                float* __restrict__ SQ10, float* __restrict__ SQ11,
                                                float* __restrict__ SQ12, float* __restrict__ SQ13,
                                                int* __restrict__ hb,
                                                float* __restrict__ outp) {
    const int PADK = 132;
    __shared__ float As[64 * PADK];
    __shared__ float colS[HD], colQ[HD], scs[HD], shs[HD];
    int t = threadIdx.x;
    int bid = blockIdx.x;
    head_phase(Gp, l1W1, nullptr, nullptr, nullptr, Hp, SQ10, bid, t, As, colS, colQ, scs, shs);
    grid_bar2(hb, 0, t);
    head_phase(Hp, l1W2, SQ10, l1g1, l1b1, Hp2, SQ11, bid, t, As, colS, colQ, scs, shs);
    grid_bar2(hb, 1, t);
    head_phase(Hp2, l2W1, SQ11, l1g2, l1b2, Hp, SQ12, bid, t, As, colS, colQ, scs, shs);
    grid_bar2(hb, 2, t);
    head_phase(Hp, l2W2, SQ12, l2g1, l2b1, Hp2, SQ13, bid, t, As, colS, colQ, scs, shs);
    grid_bar2(hb, 3, t);
    if (bid == 0) {
        if (t < HD) bn_pre(SQ13, l2g2, l2b2, 1.f / NG, t, scs, shs);
        __syncthreads();
        if (t < NG) {
            float s = 0.f;
            for (int c = 0; c < HD; c++) {
                float v = Hp2[(size_t)t * HD + c];
                v = fmaxf(fmaf(v, scs[c], shs[c]), 0.f);
                s += v * finW[c];
            }
            outp[t] = s;
        }
    }
}

extern "C" void kernel_launch(void* const* d_in, const int* in_sizes, int n_in,
                              void* d_out, int out_size, void* d_ws, size_t ws_size,
                              hipStream_t stream) {
    const int* x_ids = (const int*)d_in[0];
    const int* edge_index = (const int*)d_in[1];
    const int* batch = (const int*)d_in[2];
    const int* edge_attr = (const int*)d_in[3];
    const float* node_emb = (const float*)d_in[4];
    const float* edge_emb = (const float*)d_in[5];
    const float* eps = (const float*)d_in[6];
    const float* init_W1 = (const float*)d_in[7];
    const float* init_b1 = (const float*)d_in[8];
    const float* init_g1 = (const float*)d_in[9];
    const float* init_be1 = (const float*)d_in[10];
    const float* init_W2 = (const float*)d_in[11];
    const float* init_b2 = (const float*)d_in[12];
    const float* init_g2 = (const float*)d_in[13];
    const float* init_be2 = (const float*)d_in[14];
    const float* mp_W1 = (const float*)d_in[15];
    const float* mp_g1 = (const float*)d_in[16];
    const float* mp_be1 = (const float*)d_in[17];
    const float* mp_W2 = (const float*)d_in[18];
    const float* mp_g2 = (const float*)d_in[19];
    const float* mp_be2 = (const float*)d_in[20];
    const float* l1_W1 = (const float*)d_in[21];
    const float* l1_g1 = (const float*)d_in[22];
    const float* l1_b1 = (const float*)d_in[23];
    const float* l1_W2 = (const float*)d_in[24];
    const float* l1_g2 = (const float*)d_in[25];
    const float* l1_b2 = (const float*)d_in[26];
    const float* l2_W1 = (const float*)d_in[27];
    const float* l2_g1 = (const float*)d_in[28];
    const float* l2_b1 = (const float*)d_in[29];
    const float* l2_W2 = (const float*)d_in[30];
    const float* l2_g2 = (const float*)d_in[31];
    const float* l2_b2 = (const float*)d_in[32];
    const float* fin_W = (const float*)d_in[33];

    const int* e_src = edge_index;
    const int* e_dst = edge_index + NE;

    // workspace layout — SQ, Gp, deg, hb contiguous -> ONE memset
    const size_t STG = (size_t)REP * 256;
    float* ws = (float*)d_ws;
    float* X = ws;
    float* Bbuf = X + (size_t)NN * HD;
    unsigned short* Yb = (unsigned short*)Bbuf;      // ALIAS (lifetime disjoint)
    unsigned short* Ah = (unsigned short*)(Bbuf + (size_t)NN * HD);
    unsigned short* Al = Ah + (size_t)NN * HD;
    float* SQ = (float*)(Al + (size_t)NN * HD);      // 14 stages } zeroed
    float* Gp = SQ + 14 * STG;                       //           } as one
    int* deg = (int*)(Gp + NG * HD);                 // pad 50048 } region
    int* hb = deg + 50048;                           // 16 ints   }
    float* Hp = (float*)(hb + 16);
    float* Hp2 = Hp + NG * HD;
    int* rowptr = (int*)(Hp2 + NG * HD);
    int* cursor = rowptr + 50048;
    int* blockSum = cursor + 50048;
    int* blockOff = blockSum + 64;
    int* bucketCursor = blockOff + 64;
    unsigned* csr = (unsigned*)(bucketCursor + NB);
    unsigned short* Wh = (unsigned short*)(csr + NE);
    unsigned short* Wl = Wh + 163840;
    uint2* ebuf = (uint2*)(Wl + 163840);

    const size_t zero_bytes = (14 * STG + NG * HD) * sizeof(float) + (50048 + 16) * sizeof(int);
    hipMemsetAsync(SQ, 0, zero_bytes, stream);

    const int SCAN_BLOCKS = (NN + 1023) / 1024;  // 49
    setup_kernel<<<6890, 256, 0, stream>>>(x_ids, node_emb, Yb, init_W1, init_W2, mp_W1,
                                           mp_W2, Wh, Wl, e_dst, deg);
    scan1_kernel<<<SCAN_BLOCKS, 1024, 0, stream>>>(deg, rowptr, blockSum);
    scan2_kernel<<<1, 64, 0, stream>>>(blockSum, blockOff, rowptr, SCAN_BLOCKS);
    scan3_kernel<<<SCAN_BLOCKS, 1024, 0, stream>>>(rowptr, cursor, blockOff, bucketCursor);
    bin_kernel<<<(NE + EPB - 1) / EPB, 256, 0, stream>>>(e_src, e_dst, edge_attr,
                                                         bucketCursor, ebuf);
    place_kernel<<<(NN + 127) / 128, 256, 0, stream>>>(ebuf, rowptr, cursor, csr);

    const int mfma_grid = ((NN + 127) / 128) * 2;  // 782
    const int ybn_grid = (NN + 15) / 16;
    for (int i = 0; i <= NL; i++) {
        const unsigned short* Wh1 = Wh + (size_t)(i == 0 ? 0 : 2 + (i - 1)) * 16384;
        const unsigned short* Wl1 = Wl + (size_t)(i == 0 ? 0 : 2 + (i - 1)) * 16384;
        const unsigned short* Wh2 = Wh + (size_t)(i == 0 ? 1 : 6 + (i - 1)) * 16384;
        const unsigned short* Wl2 = Wl + (size_t)(i == 0 ? 1 : 6 + (i - 1)) * 16384;
        const float* b1 = (i == 0) ? init_b1 : nullptr;
        const float* b2 = (i == 0) ? init_b2 : nullptr;
        const float* g1 = (i == 0) ? init_g1 : mp_g1 + (size_t)(i - 1) * HD;
        const float* be1 = (i == 0) ? init_be1 : mp_be1 + (size_t)(i - 1) * HD;
        const float* gp = (i == 1) ? init_g2 : mp_g2 + (size_t)(i - 2) * HD;
        const float* bp = (i == 1) ? init_be2 : mp_be2 + (size_t)(i - 2) * HD;
        float* Sprev = SQ + (size_t)(2 * i - 1) * STG;
        float* S1 = SQ + (size_t)(2 * i) * STG;
        float* S2 = SQ + (size_t)(2 * i + 1) * STG;

        if (i > 0) ybn_kernel<<<ybn_grid, 256, 0, stream>>>(X, Sprev, gp, bp, Yb);
        conv_kernel<<<(NN + 3) / 4, 256, 0, stream>>>(Yb, rowptr, csr, edge_emb, eps, i, Ah, Al);
        mm_mfma_pre<<<mfma_grid, 256, 0, stream>>>(Ah, Al, Wh1, Wl1, b1, Bbuf, S1);
        mm_mfma_act<<<mfma_grid, 256, 0, stream>>>(Bbuf, Wh2, Wl2, b2, S1, g1, be1, X, S2);
    }

    float* S9 = SQ + 9 * STG;
    readout_kernel<<<(NN + 255) / 256, 256, 0, stream>>>(
        X, batch, S9, mp_g2 + 3 * HD, mp_be2 + 3 * HD, Gp);

    head_all<<<2, 256, 0, stream>>>(Gp, l1_W1, l1_g1, l1_b1, l1_W2, l1_g2, l1_b2,
                                    l2_W1, l2_g1, l2_b1, l2_W2, l2_g2, l2_b2, fin_W,
                                    Hp, Hp2,
                                    SQ + 10 * STG, SQ + 11 * STG, SQ + 12 * STG, SQ + 13 * STG,
                                    hb, (float*)d_out);
}

// Round 17
// 766.306 us; speedup vs baseline: 1.0202x; 1.0202x over previous
//
#include <hip/hip_runtime.h>

#define NN 50000
#define NE 800000
#define NG 128
#define HD 128
#define NL 4
#define BN_EPS 1e-5f
#define REP 32
#define WP 136
#define NB 392
#define EPB 4096

typedef __attribute__((ext_vector_type(8))) short bf16x8;
typedef __attribute__((ext_vector_type(4))) float f32x4;

__device__ __forceinline__ unsigned short f2bf(float f) {
    unsigned u = __float_as_uint(f);
    u += 0x7FFFu + ((u >> 16) & 1u);  // RNE
    return (unsigned short)(u >> 16);
}
__device__ __forceinline__ float bfval(unsigned short h) { return __uint_as_float((unsigned)h << 16); }
__device__ __forceinline__ float bflo(unsigned u) { return __uint_as_float(u << 16); }
__device__ __forceinline__ float bfhi(unsigned u) { return __uint_as_float(u & 0xFFFF0000u); }

__device__ __forceinline__ void split2(float a, float b, unsigned& hi, unsigned& lo) {
    unsigned ua = __float_as_uint(a), ub = __float_as_uint(b);
    hi = (ua >> 16) | (ub & 0xFFFF0000u);
    float ra = a - __uint_as_float(ua & 0xFFFF0000u);
    float rb = b - __uint_as_float(ub & 0xFFFF0000u);
    lo = (unsigned)f2bf(ra) | ((unsigned)f2bf(rb) << 16);
}
__device__ __forceinline__ unsigned pack2(float a, float b) {
    return (unsigned)f2bf(a) | ((unsigned)f2bf(b) << 16);
}

__device__ __forceinline__ void bn_pre(const float* SQbase,
                                       const float* gam, const float* bet,
                                       float inv_cnt, int t, float* scs, float* shs) {
    if (gam == nullptr) { scs[t] = 1.f; shs[t] = 0.f; return; }
    float s = 0.f, q = 0.f;
#pragma unroll
    for (int r = 0; r < REP; r++) {
        s += SQbase[r * 256 + t];
        q += SQbase[r * 256 + 128 + t];
    }
    float m = s * inv_cnt;
    float var = fmaxf(fmaf(q, inv_cnt, -m * m), 0.f);
    float inv = rsqrtf(var + BN_EPS);
    float sc = gam[t] * inv;
    scs[t] = sc;
    shs[t] = fmaf(-m, sc, bet[t]);
}

// ---------------- fused setup: embed (3125) | cvtw (640) | hist (3125) ----------------
__global__ __launch_bounds__(256) void setup_kernel(const int* __restrict__ ids,
                                                    const float* __restrict__ emb,
                                                    unsigned short* __restrict__ Yb,
                                                    const float* __restrict__ iw1,
                                                    const float* __restrict__ iw2,
                                                    const float* __restrict__ mw1,
                                                    const float* __restrict__ mw2,
                                                    unsigned short* __restrict__ Wh,
                                                    unsigned short* __restrict__ Wl,
                                                    const int* __restrict__ dst,
                                                    int* __restrict__ deg) {
    int b = blockIdx.x, t = threadIdx.x;
    if (b < 3125) {
        int i = b * 256 + t;
        if (i < NN * 16) {
            int node = i >> 4, g = i & 15;
            int id = ids[node];
            const float* p = emb + (size_t)id * HD + 8 * g;
            float4 a = *(const float4*)p;
            float4 bb = *(const float4*)(p + 4);
            uint4 o;
            o.x = pack2(a.x, a.y); o.y = pack2(a.z, a.w);
            o.z = pack2(bb.x, bb.y); o.w = pack2(bb.z, bb.w);
            *(uint4*)(Yb + (size_t)node * HD + 8 * g) = o;
        }
    } else if (b < 3765) {
        int i = (b - 3125) * 256 + t;
        if (i < 163840) {
            int seg = i >> 14, loc = i & 16383;
            float v;
            if (seg == 0)      v = iw1[loc];
            else if (seg == 1) v = iw2[loc];
            else if (seg < 6)  v = mw1[(seg - 2) * 16384 + loc];
            else               v = mw2[(seg - 6) * 16384 + loc];
            int k = loc >> 7, n = loc & 127;
            unsigned short h = f2bf(v);
            float r = v - bfval(h);
            Wh[seg * 16384 + n * 128 + k] = h;
            Wl[seg * 16384 + n * 128 + k] = f2bf(r);
        }
    } else {
        int e = (b - 3765) * 256 + t;
        if (e < NE) atomicAdd(&deg[dst[e]], 1);
    }
}

// ---------------- ybn ----------------
__global__ __launch_bounds__(256) void ybn_kernel(const float* __restrict__ X,
                                                  const float* __restrict__ SQin,
                                                  const float* __restrict__ gam,
                                                  const float* __restrict__ bet,
                                                  unsigned short* __restrict__ Yb) {
    __shared__ float scs[HD], shs[HD];
    int t = threadIdx.x;
    if (t < HD) bn_pre(SQin, gam, bet, 1.f / NN, t, scs, shs);
    __syncthreads();
    int row = blockIdx.x * 16 + (t >> 4);
    int c8 = (t & 15) * 8;
    if (row < NN) {
        const float* p = X + (size_t)row * HD + c8;
        float4 v0 = *(const float4*)p;
        float4 v1 = *(const float4*)(p + 4);
        float4 s0 = *(const float4*)&scs[c8], s1 = *(const float4*)&scs[c8 + 4];
        float4 h0 = *(const float4*)&shs[c8], h1 = *(const float4*)&shs[c8 + 4];
        float f0 = fmaxf(fmaf(v0.x, s0.x, h0.x), 0.f), f1 = fmaxf(fmaf(v0.y, s0.y, h0.y), 0.f);
        float f2 = fmaxf(fmaf(v0.z, s0.z, h0.z), 0.f), f3 = fmaxf(fmaf(v0.w, s0.w, h0.w), 0.f);
        float f4 = fmaxf(fmaf(v1.x, s1.x, h1.x), 0.f), f5 = fmaxf(fmaf(v1.y, s1.y, h1.y), 0.f);
        float f6 = fmaxf(fmaf(v1.z, s1.z, h1.z), 0.f), f7 = fmaxf(fmaf(v1.w, s1.w, h1.w), 0.f);
        uint4 o;
        o.x = pack2(f0, f1); o.y = pack2(f2, f3);
        o.z = pack2(f4, f5); o.w = pack2(f6, f7);
        *(uint4*)(Yb + (size_t)row * HD + c8) = o;
    }
}

// ---------------- CSR scans ----------------
__global__ __launch_bounds__(1024) void scan1_kernel(const int* __restrict__ deg,
                                                     int* __restrict__ rowptr,
                                                     int* __restrict__ blockSum) {
    __shared__ int s[1024];
    int b = blockIdx.x, t = threadIdx.x;
    int i = b * 1024 + t;
    int v = (i < NN) ? deg[i] : 0;
    s[t] = v;
    __syncthreads();
    for (int off = 1; off < 1024; off <<= 1) {
        int u = (t >= off) ? s[t - off] : 0;
        __syncthreads();
        s[t] += u;
        __syncthreads();
    }
    if (i < NN) rowptr[i] = s[t] - v;
    if (t == 1023) blockSum[b] = s[1023];
}

__global__ __launch_bounds__(64) void scan2_kernel(const int* __restrict__ blockSum,
                                                   int* __restrict__ blockOff,
                                                   int* __restrict__ rowptr, int nblocks) {
    int t = threadIdx.x;
    int orig = (t < nblocks) ? blockSum[t] : 0;
    int v = orig;
    for (int off = 1; off < 64; off <<= 1) {
        int u = __shfl_up(v, off, 64);
        if (t >= off) v += u;
    }
    if (t < nblocks) blockOff[t] = v - orig;
    if (t == nblocks - 1) rowptr[NN] = v;
}

__global__ __launch_bounds__(1024) void scan3_kernel(int* __restrict__ rowptr,
                                                     int* __restrict__ cursor,
                                                     const int* __restrict__ blockOff,
                                                     int* __restrict__ bucketCursor) {
    int b = blockIdx.x, t = threadIdx.x;
    int i = b * 1024 + t;
    if (i < NN) {
        int r = rowptr[i] + blockOff[b];
        rowptr[i] = r;
        cursor[i] = r;
        if ((i & 127) == 0) bucketCursor[i >> 7] = r;
    }
}

// ---------------- bin ----------------
__global__ __launch_bounds__(256) void bin_kernel(const int* __restrict__ src,
                                                  const int* __restrict__ dst,
                                                  const int* __restrict__ attr,
                                                  int* __restrict__ bucketCursor,
                                                  uint2* __restrict__ ebuf) {
    __shared__ int cnt[512];
    __shared__ int sc[512], sc2[512];
    __shared__ int base[512];
    __shared__ int garr[NB];
    __shared__ int wof[NB];
    __shared__ uint2 stage[EPB];
    int t = threadIdx.x;
    int e0 = blockIdx.x * EPB;
    for (int i = t; i < 512; i += 256) cnt[i] = 0;
    __syncthreads();
    int myb[16]; unsigned myv[16]; int myd[16];
#pragma unroll
    for (int j = 0; j < 16; j++) {
        int e = e0 + t + j * 256;
        if (e < NE) {
            int d = dst[e];
            myd[j] = d;
            myv[j] = (unsigned)src[e] | ((unsigned)attr[e] << 16);
            myb[j] = d >> 7;
            atomicAdd(&cnt[myb[j]], 1);
        } else myb[j] = -1;
    }
    __syncthreads();
    for (int k = t; k < 512; k += 256) sc[k] = cnt[k];
    __syncthreads();
    int* sp = sc; int* dp = sc2;
    for (int off = 1; off < 512; off <<= 1) {
        for (int k = t; k < 512; k += 256) dp[k] = sp[k] + (k >= off ? sp[k - off] : 0);
        __syncthreads();
        int* tmp = sp; sp = dp; dp = tmp;
    }
    for (int k = t; k < 512; k += 256) base[k] = sp[k] - cnt[k];
    int total = sp[511];
    __syncthreads();
    for (int b = t; b < NB; b += 256) {
        wof[b] = 0;
        if (cnt[b] > 0) garr[b] = atomicAdd(&bucketCursor[b], cnt[b]);
    }
    __syncthreads();
#pragma unroll
    for (int j = 0; j < 16; j++) {
        if (myb[j] >= 0) {
            int slot = base[myb[j]] + atomicAdd(&wof[myb[j]], 1);
            stage[slot] = make_uint2(myv[j], (unsigned)myd[j]);
        }
    }
    __syncthreads();
    for (int i = t; i < total; i += 256) {
        uint2 u = stage[i];
        int b = (int)(u.y >> 7);
        ebuf[garr[b] + (i - base[b])] = u;
    }
}

// ---------------- place ----------------
__global__ __launch_bounds__(256) void place_kernel(const uint2* __restrict__ ebuf,
                                                    const int* __restrict__ rowptr,
                                                    int* __restrict__ cursor,
                                                    unsigned* __restrict__ csr) {
    int b = blockIdx.x;
    int n0 = b * 128;
    int n1 = n0 + 128; if (n1 > NN) n1 = NN;
    int es = rowptr[n0], ee = rowptr[n1];
    for (int i = es + threadIdx.x; i < ee; i += 256) {
        uint2 u = ebuf[i];
        int pos = atomicAdd(&cursor[u.y], 1);
        csr[pos] = u.x;
    }
}

// ---------------- GINE conv ----------------
__device__ __forceinline__ void gine_acc(const unsigned short* __restrict__ Yb,
                                         const float* __restrict__ elds,
                                         unsigned p, int cq, float mask, float* a) {
    uint4 q = *(const uint4*)(Yb + (size_t)(p & 0xFFFFu) * HD + 8 * cq);
    const float* ep = elds + (p >> 16) * HD + 8 * cq;
    float4 e0 = *(const float4*)ep;
    float4 e1 = *(const float4*)(ep + 4);
    a[0] += mask * fmaxf(bflo(q.x) + e0.x, 0.f);
    a[1] += mask * fmaxf(bfhi(q.x) + e0.y, 0.f);
    a[2] += mask * fmaxf(bflo(q.y) + e0.z, 0.f);
    a[3] += mask * fmaxf(bfhi(q.y) + e0.w, 0.f);
    a[4] += mask * fmaxf(bflo(q.z) + e1.x, 0.f);
    a[5] += mask * fmaxf(bfhi(q.z) + e1.y, 0.f);
    a[6] += mask * fmaxf(bflo(q.w) + e1.z, 0.f);
    a[7] += mask * fmaxf(bfhi(q.w) + e1.w, 0.f);
}

__global__ __launch_bounds__(256) void conv_kernel(const unsigned short* __restrict__ Yb,
                                                   const int* __restrict__ rowptr,
                                                   const unsigned* __restrict__ csr,
                                                   const float* __restrict__ edge_emb,
                                                   const float* __restrict__ eps, int layer,
                                                   unsigned short* __restrict__ Ah,
                                                   unsigned short* __restrict__ Al) {
    __shared__ float elds[8 * HD];
    int t = threadIdx.x;
    ((float4*)elds)[t] = ((const float4*)edge_emb)[t];
    __syncthreads();
    int wave = t >> 6, lane = t & 63;
    int node = blockIdx.x * 4 + wave;
    if (node >= NN) return;
    int sub = lane >> 4, cq = lane & 15;
    int lo = rowptr[node], hi = rowptr[node + 1];
    float a[8];
#pragma unroll
    for (int i = 0; i < 8; i++) a[i] = 0.f;
    for (int base = lo; base < hi; base += 64) {
        unsigned pl = 0;
        int cnt = hi - base; if (cnt > 64) cnt = 64;
        if (base + lane < hi) pl = csr[base + lane];
        int j = 0;
        for (; j + 16 <= cnt; j += 16) {
            unsigned pa = __shfl(pl, j + sub, 64);
            unsigned pb = __shfl(pl, j + 4 + sub, 64);
            unsigned pc = __shfl(pl, j + 8 + sub, 64);
            unsigned pd = __shfl(pl, j + 12 + sub, 64);
            gine_acc(Yb, elds, pa, cq, 1.f, a);
            gine_acc(Yb, elds, pb, cq, 1.f, a);
            gine_acc(Yb, elds, pc, cq, 1.f, a);
            gine_acc(Yb, elds, pd, cq, 1.f, a);
        }
        for (; j + 8 <= cnt; j += 8) {
            unsigned pa = __shfl(pl, j + sub, 64);
            unsigned pb = __shfl(pl, j + 4 + sub, 64);
            gine_acc(Yb, elds, pa, cq, 1.f, a);
            gine_acc(Yb, elds, pb, cq, 1.f, a);
        }
        for (; j < cnt; j += 4) {
            int je = j + sub;
            bool val = (je < cnt);
            unsigned p = __shfl(pl, val ? je : j, 64);
            gine_acc(Yb, elds, p, cq, val ? 1.f : 0.f, a);
        }
    }
#pragma unroll
    for (int i = 0; i < 8; i++) {
        a[i] += __shfl_xor(a[i], 16, 64);
        a[i] += __shfl_xor(a[i], 32, 64);
    }
    if (sub == 0) {
        float g = 1.f + eps[layer];
        uint4 q = *(const uint4*)(Yb + (size_t)node * HD + 8 * cq);
        float o0 = fmaf(g, bflo(q.x), a[0]), o1 = fmaf(g, bfhi(q.x), a[1]);
        float o2 = fmaf(g, bflo(q.y), a[2]), o3 = fmaf(g, bfhi(q.y), a[3]);
        float o4 = fmaf(g, bflo(q.z), a[4]), o5 = fmaf(g, bfhi(q.z), a[5]);
        float o6 = fmaf(g, bflo(q.w), a[6]), o7 = fmaf(g, bfhi(q.w), a[7]);
        uint4 H, L;
        split2(o0, o1, H.x, L.x);
        split2(o2, o3, H.y, L.y);
        split2(o4, o5, H.z, L.z);
        split2(o6, o7, H.w, L.w);
        *(uint4*)(Ah + (size_t)node * HD + 8 * cq) = H;
        *(uint4*)(Al + (size_t)node * HD + 8 * cq) = L;
    }
}

// ---------------- MFMA matmul, pre-split A, W in LDS; 2 row-tiles/wave ----------------
__global__ __launch_bounds__(256) void mm_mfma_pre(const unsigned short* __restrict__ Ah,
                                                   const unsigned short* __restrict__ Al,
                                                   const unsigned short* __restrict__ Wh,
                                                   const unsigned short* __restrict__ Wl,
                                                   const float* __restrict__ bias,
                                                   float* __restrict__ out,
                                                   float* __restrict__ SQout) {
    __shared__ unsigned short WhS[64 * WP];
    __shared__ unsigned short WlS[64 * WP];
    int t = threadIdx.x;
    int rowblk = blockIdx.x >> 1;
    int colbase = (blockIdx.x & 1) * 64;
    const unsigned short* sh = Wh + (size_t)colbase * HD;
    const unsigned short* sl = Wl + (size_t)colbase * HD;
#pragma unroll
    for (int i = 0; i < 4; i++) {
        int idx = t + i * 256;
        int col = idx >> 4, kk = (idx & 15) * 8;
        *(uint4*)(WhS + col * WP + kk) = *(const uint4*)(sh + (size_t)col * HD + kk);
        *(uint4*)(WlS + col * WP + kk) = *(const uint4*)(sl + (size_t)col * HD + kk);
    }
    __syncthreads();
    int w = t >> 6, lane = t & 63;
    int quad = lane >> 4, nl = lane & 15;
    int row0 = rowblk * 128 + w * 32;
    int rA0 = row0 + nl, rA1 = row0 + 16 + nl;
    bool ok0 = rA0 < NN, ok1 = rA1 < NN;
    f32x4 acc[8];
#pragma unroll
    for (int i = 0; i < 8; i++) acc[i] = (f32x4){0.f, 0.f, 0.f, 0.f};
#pragma unroll
    for (int kc = 0; kc < 4; kc++) {
        int k0 = kc * 32 + quad * 8;
        bf16x8 a0h = ok0 ? *(const bf16x8*)(Ah + (size_t)rA0 * HD + k0) : (bf16x8)0;
        bf16x8 a0l = ok0 ? *(const bf16x8*)(Al + (size_t)rA0 * HD + k0) : (bf16x8)0;
        bf16x8 a1h = ok1 ? *(const bf16x8*)(Ah + (size_t)rA1 * HD + k0) : (bf16x8)0;
        bf16x8 a1l = ok1 ? *(const bf16x8*)(Al + (size_t)rA1 * HD + k0) : (bf16x8)0;
#pragma unroll
        for (int c = 0; c < 4; c++) {
            int wof = (c * 16 + nl) * WP + k0;
            bf16x8 bh = *(const bf16x8*)(WhS + wof);
            bf16x8 bl = *(const bf16x8*)(WlS + wof);
            acc[c] = __builtin_amdgcn_mfma_f32_16x16x32_bf16(a0h, bh, acc[c], 0, 0, 0);
            acc[c] = __builtin_amdgcn_mfma_f32_16x16x32_bf16(a0l, bh, acc[c], 0, 0, 0);
            acc[c] = __builtin_amdgcn_mfma_f32_16x16x32_bf16(a0h, bl, acc[c], 0, 0, 0);
            acc[4 + c] = __builtin_amdgcn_mfma_f32_16x16x32_bf16(a1h, bh, acc[4 + c], 0, 0, 0);
            acc[4 + c] = __builtin_amdgcn_mfma_f32_16x16x32_bf16(a1l, bh, acc[4 + c], 0, 0, 0);
            acc[4 + c] = __builtin_amdgcn_mfma_f32_16x16x32_bf16(a1h, bl, acc[4 + c], 0, 0, 0);
        }
    }
    int rep = (blockIdx.x & (REP - 1)) * 256;
#pragma unroll
    for (int h = 0; h < 2; h++) {
        int baserow = row0 + h * 16 + quad * 4;
#pragma unroll
        for (int c = 0; c < 4; c++) {
            int col = colbase + c * 16 + nl;
            float bv = bias ? bias[col] : 0.f;
            f32x4 v = acc[h * 4 + c];
            float s = 0.f, qq = 0.f;
#pragma unroll
            for (int r = 0; r < 4; r++) {
                int grow = baserow + r;
                float val = v[r] + bv;
                if (grow < NN) {
                    out[(size_t)grow * HD + col] = val;
                    s += val;
                    qq += val * val;
                }
            }
            s += __shfl_xor(s, 16, 64);  s += __shfl_xor(s, 32, 64);
            qq += __shfl_xor(qq, 16, 64); qq += __shfl_xor(qq, 32, 64);
            if (quad == 0) {
                atomicAdd(&SQout[rep + col], s);
                atomicAdd(&SQout[rep + 128 + col], qq);
            }
        }
    }
}

// ---------------- MFMA matmul, fp32 A + fused BN-act + split, W in LDS; 2 row-tiles ----------
__global__ __launch_bounds__(256) void mm_mfma_act(const float* __restrict__ A,
                                                   const unsigned short* __restrict__ Wh,
                                                   const unsigned short* __restrict__ Wl,
                                                   const float* __restrict__ bias,
                                                   const float* __restrict__ SQin,
                                                   const float* __restrict__ gam,
                                                   const float* __restrict__ bet,
                                                   float* __restrict__ out,
                                                   float* __restrict__ SQout) {
    __shared__ unsigned short WhS[64 * WP];
    __shared__ unsigned short WlS[64 * WP];
    __shared__ float scs[HD], shs[HD];
    int t = threadIdx.x;
    int rowblk = blockIdx.x >> 1;
    int colbase = (blockIdx.x & 1) * 64;
    if (t < HD) bn_pre(SQin, gam, bet, 1.f / NN, t, scs, shs);
    const unsigned short* sh = Wh + (size_t)colbase * HD;
    const unsigned short* sl = Wl + (size_t)colbase * HD;
#pragma unroll
    for (int i = 0; i < 4; i++) {
        int idx = t + i * 256;
        int col = idx >> 4, kk = (idx & 15) * 8;
        *(uint4*)(WhS + col * WP + kk) = *(const uint4*)(sh + (size_t)col * HD + kk);
        *(uint4*)(WlS + col * WP + kk) = *(const uint4*)(sl + (size_t)col * HD + kk);
    }
    __syncthreads();
    int w = t >> 6, lane = t & 63;
    int quad = lane >> 4, nl = lane & 15;
    int row0 = rowblk * 128 + w * 32;
    int rA0 = row0 + nl, rA1 = row0 + 16 + nl;
    bool ok0 = rA0 < NN, ok1 = rA1 < NN;
    f32x4 acc[8];
#pragma unroll
    for (int i = 0; i < 8; i++) acc[i] = (f32x4){0.f, 0.f, 0.f, 0.f};
#pragma unroll
    for (int kc = 0; kc < 4; kc++) {
        int k0 = kc * 32 + quad * 8;
        float4 s0 = *(const float4*)&scs[k0], s1 = *(const float4*)&scs[k0 + 4];
        float4 t0 = *(const float4*)&shs[k0], t1 = *(const float4*)&shs[k0 + 4];
        bf16x8 a0h, a0l, a1h, a1l;
        {
            float4 v0 = ok0 ? *(const float4*)(A + (size_t)rA0 * HD + k0) : make_float4(0, 0, 0, 0);
            float4 v1 = ok0 ? *(const float4*)(A + (size_t)rA0 * HD + k0 + 4) : make_float4(0, 0, 0, 0);
            float f0 = fmaxf(fmaf(v0.x, s0.x, t0.x), 0.f), f1 = fmaxf(fmaf(v0.y, s0.y, t0.y), 0.f);
            float f2 = fmaxf(fmaf(v0.z, s0.z, t0.z), 0.f), f3 = fmaxf(fmaf(v0.w, s0.w, t0.w), 0.f);
            float f4 = fmaxf(fmaf(v1.x, s1.x, t1.x), 0.f), f5 = fmaxf(fmaf(v1.y, s1.y, t1.y), 0.f);
            float f6 = fmaxf(fmaf(v1.z, s1.z, t1.z), 0.f), f7 = fmaxf(fmaf(v1.w, s1.w, t1.w), 0.f);
            if (!ok0) { f0 = f1 = f2 = f3 = f4 = f5 = f6 = f7 = 0.f; }
            unsigned h0, h1, h2, h3, l0, l1, l2, l3;
            split2(f0, f1, h0, l0); split2(f2, f3, h1, l1);
            split2(f4, f5, h2, l2); split2(f6, f7, h3, l3);
            a0h = __builtin_bit_cast(bf16x8, make_uint4(h0, h1, h2, h3));
            a0l = __builtin_bit_cast(bf16x8, make_uint4(l0, l1, l2, l3));
        }
        {
            float4 v0 = ok1 ? *(const float4*)(A + (size_t)rA1 * HD + k0) : make_float4(0, 0, 0, 0);
            float4 v1 = ok1 ? *(const float4*)(A + (size_t)rA1 * HD + k0 + 4) : make_float4(0, 0, 0, 0);
            float f0 = fmaxf(fmaf(v0.x, s0.x, t0.x), 0.f), f1 = fmaxf(fmaf(v0.y, s0.y, t0.y), 0.f);
            float f2 = fmaxf(fmaf(v0.z, s0.z, t0.z), 0.f), f3 = fmaxf(fmaf(v0.w, s0.w, t0.w), 0.f);
            float f4 = fmaxf(fmaf(v1.x, s1.x, t1.x), 0.f), f5 = fmaxf(fmaf(v1.y, s1.y, t1.y), 0.f);
            float f6 = fmaxf(fmaf(v1.z, s1.z, t1.z), 0.f), f7 = fmaxf(fmaf(v1.w, s1.w, t1.w), 0.f);
            if (!ok1) { f0 = f1 = f2 = f3 = f4 = f5 = f6 = f7 = 0.f; }
            unsigned h0, h1, h2, h3, l0, l1, l2, l3;
            split2(f0, f1, h0, l0); split2(f2, f3, h1, l1);
            split2(f4, f5, h2, l2); split2(f6, f7, h3, l3);
            a1h = __builtin_bit_cast(bf16x8, make_uint4(h0, h1, h2, h3));
            a1l = __builtin_bit_cast(bf16x8, make_uint4(l0, l1, l2, l3));
        }
#pragma unroll
        for (int c = 0; c < 4; c++) {
            int wof = (c * 16 + nl) * WP + k0;
            bf16x8 bh = *(const bf16x8*)(WhS + wof);
            bf16x8 bl = *(const bf16x8*)(WlS + wof);
            acc[c] = __builtin_amdgcn_mfma_f32_16x16x32_bf16(a0h, bh, acc[c], 0, 0, 0);
            acc[c] = __builtin_amdgcn_mfma_f32_16x16x32_bf16(a0l, bh, acc[c], 0, 0, 0);
            acc[c] = __builtin_amdgcn_mfma_f32_16x16x32_bf16(a0h, bl, acc[c], 0, 0, 0);
            acc[4 + c] = __builtin_amdgcn_mfma_f32_16x16x32_bf16(a1h, bh, acc[4 + c], 0, 0, 0);
            acc[4 + c] = __builtin_amdgcn_mfma_f32_16x16x32_bf16(a1l, bh, acc[4 + c], 0, 0, 0);
            acc[4 + c] = __builtin_amdgcn_mfma_f32_16x16x32_bf16(a1h, bl, acc[4 + c], 0, 0, 0);
        }
    }
    int rep = (blockIdx.x & (REP - 1)) * 256;
#pragma unroll
    for (int h = 0; h < 2; h++) {
        int baserow = row0 + h * 16 + quad * 4;
#pragma unroll
        for (int c = 0; c < 4; c++) {
            int col = colbase + c * 16 + nl;
            float bv = bias ? bias[col] : 0.f;
            f32x4 v = acc[h * 4 + c];
            float s = 0.f, qq = 0.f;
#pragma unroll
            for (int r = 0; r < 4; r++) {
                int grow = baserow + r;
                float val = v[r] + bv;
                if (grow < NN) {
                    out[(size_t)grow * HD + col] = val;
                    s += val;
                    qq += val * val;
                }
            }
            s += __shfl_xor(s, 16, 64);  s += __shfl_xor(s, 32, 64);
            qq += __shfl_xor(qq, 16, 64); qq += __shfl_xor(qq, 32, 64);
            if (quad == 0) {
                atomicAdd(&SQout[rep + col], s);
                atomicAdd(&SQout[rep + 128 + col], qq);
            }
        }
    }
}

// ---------------- readout ----------------
__global__ __launch_bounds__(256) void readout_kernel(const float* __restrict__ x,
                                                      const int* __restrict__ batch,
                                                      const float* __restrict__ SQin,
                                                      const float* __restrict__ gam,
                                                      const float* __restrict__ bet,
                                                      float* __restrict__ gout) {
    __shared__ int bat[256];
    __shared__ float scs[HD], shs[HD];
    int t = threadIdx.x;
    int rq = t >> 5, cq = t & 31;
    int r0 = blockIdx.x * 256;
    int i = r0 + t;
    bat[t] = (i < NN) ? batch[i] : -1;
    if (t < HD) bn_pre(SQin, gam, bet, 1.f / NN, t, scs, shs);
    __syncthreads();
    float4 s4 = *(const float4*)&scs[4 * cq];
    float4 h4 = *(const float4*)&shs[4 * cq];
    float4 acc = make_float4(0.f, 0.f, 0.f, 0.f);
    int gcur = -1;
    for (int j = rq; j < 256; j += 8) {
        int r = r0 + j;
        if (r >= NN) break;
        int g = bat[j];
        if (g != gcur) {
            if (gcur >= 0) {
                atomicAdd(&gout[(size_t)gcur * HD + 4 * cq + 0], acc.x);
                atomicAdd(&gout[(size_t)gcur * HD + 4 * cq + 1], acc.y);
                atomicAdd(&gout[(size_t)gcur * HD + 4 * cq + 2], acc.z);
                atomicAdd(&gout[(size_t)gcur * HD + 4 * cq + 3], acc.w);
            }
            acc = make_float4(0.f, 0.f, 0.f, 0.f);
            gcur = g;
        }
        float4 v = *(const float4*)(x + (size_t)r * HD + 4 * cq);
        acc.x += fmaxf(fmaf(v.x, s4.x, h4.x), 0.f);
        acc.y += fmaxf(fmaf(v.y, s4.y, h4.y), 0.f);
        acc.z += fmaxf(fmaf(v.z, s4.z, h4.z), 0.f);
        acc.w += fmaxf(fmaf(v.w, s4.w, h4.w), 0.f);
    }
    if (gcur >= 0) {
        atomicAdd(&gout[(size_t)gcur * HD + 4 * cq + 0], acc.x);
        atomicAdd(&gout[(size_t)gcur * HD + 4 * cq + 1], acc.y);
        atomicAdd(&gout[(size_t)gcur * HD + 4 * cq + 2], acc.z);
        atomicAdd(&gout[(size_t)gcur * HD + 4 * cq + 3], acc.w);
    }
}

// ---------------- head: fp32 matmul (128 rows), BN-from-stats preamble ----------------
__global__ __launch_bounds__(256) void head_mm(const float* __restrict__ A,
                                               const float* __restrict__ W,
                                               const float* __restrict__ SQin,
                                               const float* __restrict__ gam,
                                               const float* __restrict__ bet,
                                               float* __restrict__ out,
                                               float* __restrict__ SQout) {
    const int PADK = 132;
    __shared__ float As[64 * PADK];
    __shared__ float colS[HD], colQ[HD];
    __shared__ float scs[HD], shs[HD];
    int t = threadIdx.x;
    if (t < HD) {
        colS[t] = 0.f; colQ[t] = 0.f;
        bn_pre(SQin, gam, bet, 1.f / NG, t, scs, shs);
    }
    __syncthreads();
    int row0 = blockIdx.x * 64;
#pragma unroll
    for (int i = 0; i < 8; i++) {
        int idx = t + i * 256;
        int r = idx >> 5, kq = idx & 31;
        float4 v = *(const float4*)(A + (size_t)(row0 + r) * HD + 4 * kq);
        float4 s4 = *(const float4*)&scs[4 * kq];
        float4 h4 = *(const float4*)&shs[4 * kq];
        v.x = fmaxf(fmaf(v.x, s4.x, h4.x), 0.f);
        v.y = fmaxf(fmaf(v.y, s4.y, h4.y), 0.f);
        v.z = fmaxf(fmaf(v.z, s4.z, h4.z), 0.f);
        v.w = fmaxf(fmaf(v.w, s4.w, h4.w), 0.f);
        *(float4*)&As[r * PADK + 4 * kq] = v;
    }
    __syncthreads();
    int jq = t & 31, rb = t >> 5;
    float acc[8][4];
#pragma unroll
    for (int i = 0; i < 8; i++)
#pragma unroll
        for (int j = 0; j < 4; j++) acc[i][j] = 0.f;
    const float* Wp = W + 4 * jq;
    const float* Ap = &As[rb * 8 * PADK];
    for (int k = 0; k < HD; k += 4) {
        float4 w0 = *(const float4*)(Wp + (size_t)(k + 0) * HD);
        float4 w1 = *(const float4*)(Wp + (size_t)(k + 1) * HD);
        float4 w2 = *(const float4*)(Wp + (size_t)(k + 2) * HD);
        float4 w3 = *(const float4*)(Wp + (size_t)(k + 3) * HD);
#pragma unroll
        for (int i = 0; i < 8; i++) {
            float4 a4 = *(const float4*)&Ap[i * PADK + k];
            acc[i][0] = fmaf(a4.x, w0.x, acc[i][0]);
            acc[i][1] = fmaf(a4.x, w0.y, acc[i][1]);
            acc[i][2] = fmaf(a4.x, w0.z, acc[i][2]);
            acc[i][3] = fmaf(a4.x, w0.w, acc[i][3]);
            acc[i][0] = fmaf(a4.y, w1.x, acc[i][0]);
            acc[i][1] = fmaf(a4.y, w1.y, acc[i][1]);
            acc[i][2] = fmaf(a4.y, w1.z, acc[i][2]);
            acc[i][3] = fmaf(a4.y, w1.w, acc[i][3]);
            acc[i][0] = fmaf(a4.z, w2.x, acc[i][0]);
            acc[i][1] = fmaf(a4.z, w2.y, acc[i][1]);
            acc[i][2] = fmaf(a4.z, w2.z, acc[i][2]);
            acc[i][3] = fmaf(a4.z, w2.w, acc[i][3]);
            acc[i][0] = fmaf(a4.w, w3.x, acc[i][0]);
            acc[i][1] = fmaf(a4.w, w3.y, acc[i][1]);
            acc[i][2] = fmaf(a4.w, w3.z, acc[i][2]);
            acc[i][3] = fmaf(a4.w, w3.w, acc[i][3]);
        }
    }
    float s0 = 0, s1 = 0, s2 = 0, s3 = 0, q0 = 0, q1 = 0, q2 = 0, q3 = 0;
#pragma unroll
    for (int i = 0; i < 8; i++) {
        int gr = row0 + rb * 8 + i;
        float4 v = make_float4(acc[i][0], acc[i][1], acc[i][2], acc[i][3]);
        *(float4*)(out + (size_t)gr * HD + 4 * jq) = v;
        s0 += v.x; q0 += v.x * v.x;
        s1 += v.y; q1 += v.y * v.y;
        s2 += v.z; q2 += v.z * v.z;
        s3 += v.w; q3 += v.w * v.w;
    }
    atomicAdd(&colS[4 * jq + 0], s0); atomicAdd(&colQ[4 * jq + 0], q0);
    atomicAdd(&colS[4 * jq + 1], s1); atomicAdd(&colQ[4 * jq + 1], q1);
    atomicAdd(&colS[4 * jq + 2], s2); atomicAdd(&colQ[4 * jq + 2], q2);
    atomicAdd(&colS[4 * jq + 3], s3); atomicAdd(&colQ[4 * jq + 3], q3);
    __syncthreads();
    int rep = (blockIdx.x & (REP - 1)) * 256;
    if (t < HD) {
        atomicAdd(&SQout[rep + t], colS[t]);
        atomicAdd(&SQout[rep + 128 + t], colQ[t]);
    }
}

// ---------------- final ----------------
__global__ __launch_bounds__(128) void final_kernel(const float* __restrict__ h,
                                                    const float* __restrict__ SQin,
                                                    const float* __restrict__ gam,
                                                    const float* __restrict__ bet,
                                                    const float* __restrict__ finW,
                                                    float* __restrict__ out) {
    __shared__ float scs[HD], shs[HD];
    int t = threadIdx.x;
    bn_pre(SQin, gam, bet, 1.f / NG, t, scs, shs);
    __syncthreads();
    float s = 0.f;
    for (int c = 0; c < HD; c++) {
        float v = h[(size_t)t * HD + c];
        v = fmaxf(fmaf(v, scs[c], shs[c]), 0.f);
        s += v * finW[c];
    }
    out[t] = s;
}

extern "C" void kernel_launch(void* const* d_in, const int* in_sizes, int n_in,
                              void* d_out, int out_size, void* d_ws, size_t ws_size,
                              hipStream_t stream) {
    const int* x_ids = (const int*)d_in[0];
    const int* edge_index = (const int*)d_in[1];
    const int* batch = (const int*)d_in[2];
    const int* edge_attr = (const int*)d_in[3];
    const float* node_emb = (const float*)d_in[4];
    const float* edge_emb = (const float*)d_in[5];
    const float* eps = (const float*)d_in[6];
    const float* init_W1 = (const float*)d_in[7];
    const float* init_b1 = (const float*)d_in[8];
    const float* init_g1 = (const float*)d_in[9];
    const float* init_be1 = (const float*)d_in[10];
    const float* init_W2 = (const float*)d_in[11];
    const float* init_b2 = (const float*)d_in[12];
    const float* init_g2 = (const float*)d_in[13];
    const float* init_be2 = (const float*)d_in[14];
    const float* mp_W1 = (const float*)d_in[15];
    const float* mp_g1 = (const float*)d_in[16];
    const float* mp_be1 = (const float*)d_in[17];
    const float* mp_W2 = (const float*)d_in[18];
    const float* mp_g2 = (const float*)d_in[19];
    const float* mp_be2 = (const float*)d_in[20];
    const float* l1_W1 = (const float*)d_in[21];
    const float* l1_g1 = (const float*)d_in[22];
    const float* l1_b1 = (const float*)d_in[23];
    const float* l1_W2 = (const float*)d_in[24];
    const float* l1_g2 = (const float*)d_in[25];
    const float* l1_b2 = (const float*)d_in[26];
    const float* l2_W1 = (const float*)d_in[27];
    const float* l2_g1 = (const float*)d_in[28];
    const float* l2_b1 = (const float*)d_in[29];
    const float* l2_W2 = (const float*)d_in[30];
    const float* l2_g2 = (const float*)d_in[31];
    const float* l2_b2 = (const float*)d_in[32];
    const float* fin_W = (const float*)d_in[33];

    const int* e_src = edge_index;
    const int* e_dst = edge_index + NE;

    // workspace layout — SQ, Gp, deg contiguous -> ONE memset
    const size_t STG = (size_t)REP * 256;
    float* ws = (float*)d_ws;
    float* X = ws;
    float* Bbuf = X + (size_t)NN * HD;
    unsigned short* Yb = (unsigned short*)Bbuf;      // ALIAS (lifetime disjoint)
    unsigned short* Ah = (unsigned short*)(Bbuf + (size_t)NN * HD);
    unsigned short* Al = Ah + (size_t)NN * HD;
    float* SQ = (float*)(Al + (size_t)NN * HD);      // 14 stages } zeroed
    float* Gp = SQ + 14 * STG;                       //           } as one
    int* deg = (int*)(Gp + NG * HD);                 // pad 50048 } region
    float* Hp = (float*)(deg + 50048);
    float* Hp2 = Hp + NG * HD;
    int* rowptr = (int*)(Hp2 + NG * HD);
    int* cursor = rowptr + 50048;
    int* blockSum = cursor + 50048;
    int* blockOff = blockSum + 64;
    int* bucketCursor = blockOff + 64;
    unsigned* csr = (unsigned*)(bucketCursor + NB);
    unsigned short* Wh = (unsigned short*)(csr + NE);
    unsigned short* Wl = Wh + 163840;
    uint2* ebuf = (uint2*)(Wl + 163840);

    const size_t zero_bytes = (14 * STG + NG * HD) * sizeof(float) + 50048 * sizeof(int);
    hipMemsetAsync(SQ, 0, zero_bytes, stream);

    const int SCAN_BLOCKS = (NN + 1023) / 1024;  // 49
    setup_kernel<<<6890, 256, 0, stream>>>(x_ids, node_emb, Yb, init_W1, init_W2, mp_W1,
                                           mp_W2, Wh, Wl, e_dst, deg);
    scan1_kernel<<<SCAN_BLOCKS, 1024, 0, stream>>>(deg, rowptr, blockSum);
    scan2_kernel<<<1, 64, 0, stream>>>(blockSum, blockOff, rowptr, SCAN_BLOCKS);
    scan3_kernel<<<SCAN_BLOCKS, 1024, 0, stream>>>(rowptr, cursor, blockOff, bucketCursor);
    bin_kernel<<<(NE + EPB - 1) / EPB, 256, 0, stream>>>(e_src, e_dst, edge_attr,
                                                         bucketCursor, ebuf);
    place_kernel<<<(NN + 127) / 128, 256, 0, stream>>>(ebuf, rowptr, cursor, csr);

    const int mfma_grid = ((NN + 127) / 128) * 2;  // 782
    const int ybn_grid = (NN + 15) / 16;
    for (int i = 0; i <= NL; i++) {
        const unsigned short* Wh1 = Wh + (size_t)(i == 0 ? 0 : 2 + (i - 1)) * 16384;
        const unsigned short* Wl1 = Wl + (size_t)(i == 0 ? 0 : 2 + (i - 1)) * 16384;
        const unsigned short* Wh2 = Wh + (size_t)(i == 0 ? 1 : 6 + (i - 1)) * 16384;
        const unsigned short* Wl2 = Wl + (size_t)(i == 0 ? 1 : 6 + (i - 1)) * 16384;
        const float* b1 = (i == 0) ? init_b1 : nullptr;
        const float* b2 = (i == 0) ? init_b2 : nullptr;
        const float* g1 = (i == 0) ? init_g1 : mp_g1 + (size_t)(i - 1) * HD;
        const float* be1 = (i == 0) ? init_be1 : mp_be1 + (size_t)(i - 1) * HD;
        const float* gp = (i == 1) ? init_g2 : mp_g2 + (size_t)(i - 2) * HD;
        const float* bp = (i == 1) ? init_be2 : mp_be2 + (size_t)(i - 2) * HD;
        float* Sprev = SQ + (size_t)(2 * i - 1) * STG;
        float* S1 = SQ + (size_t)(2 * i) * STG;
        float* S2 = SQ + (size_t)(2 * i + 1) * STG;

        if (i > 0) ybn_kernel<<<ybn_grid, 256, 0, stream>>>(X, Sprev, gp, bp, Yb);
        conv_kernel<<<(NN + 3) / 4, 256, 0, stream>>>(Yb, rowptr, csr, edge_emb, eps, i, Ah, Al);
        mm_mfma_pre<<<mfma_grid, 256, 0, stream>>>(Ah, Al, Wh1, Wl1, b1, Bbuf, S1);
        mm_mfma_act<<<mfma_grid, 256, 0, stream>>>(Bbuf, Wh2, Wl2, b2, S1, g1, be1, X, S2);
    }

    float* S9 = SQ + 9 * STG;
    readout_kernel<<<(NN + 255) / 256, 256, 0, stream>>>(
        X, batch, S9, mp_g2 + 3 * HD, mp_be2 + 3 * HD, Gp);

    float* S10 = SQ + 10 * STG;
    float* S11 = SQ + 11 * STG;
    float* S12 = SQ + 12 * STG;
    float* S13 = SQ + 13 * STG;
    head_mm<<<2, 256, 0, stream>>>(Gp, l1_W1, nullptr, nullptr, nullptr, Hp, S10);
    head_mm<<<2, 256, 0, stream>>>(Hp, l1_W2, S10, l1_g1, l1_b1, Hp2, S11);
    head_mm<<<2, 256, 0, stream>>>(Hp2, l2_W1, S11, l1_g2, l1_b2, Hp, S12);
    head_mm<<<2, 256, 0, stream>>>(Hp, l2_W2, S12, l2_g1, l2_b1, Hp2, S13);
    final_kernel<<<1, 128, 0, stream>>>(Hp2, S13, l2_g2, l2_b2, fin_W, (float*)d_out);
}